// Round 1
// baseline (1402.920 us; speedup 1.0000x reference)
//
#include <hip/hip_runtime.h>

// Problem constants (fixed by reference)
#define R_   3
#define N_   50000
#define E_   400000
#define IN_  128
#define HID_ 64
#define C_   40
#define H_   3
#define NEG_SLOPE 0.2f

// scan chunking: 1024 elements per block (256 thr x 4)
#define SCAN_CHUNK 1024
#define NCH  49      // ceil(N_/1024)
#define NCH2 64      // padded stride

// ---------------- utility ----------------
__global__ void zero_kernel(float* __restrict__ p, size_t n) {
    size_t i = (size_t)blockIdx.x * blockDim.x + threadIdx.x;
    if (i < n) p[i] = 0.f;
}

// ---------------- CSR build ----------------
__global__ void hist_kernel(const int* __restrict__ dst, int* __restrict__ deg) {
    int idx = blockIdx.x * 256 + threadIdx.x;
    if (idx < R_ * E_) {
        int r = idx / E_;
        atomicAdd(&deg[r * N_ + dst[idx]], 1);
    }
}

__global__ void scanA_kernel(const int* __restrict__ deg, int* __restrict__ bsum) {
    int r = blockIdx.y, ch = blockIdx.x, tid = threadIdx.x;
    int base = ch * SCAN_CHUNK + tid * 4;
    int s = 0;
    for (int j = 0; j < 4; ++j) {
        int i = base + j;
        if (i < N_) s += deg[r * N_ + i];
    }
    __shared__ int red[256];
    red[tid] = s; __syncthreads();
    for (int off = 128; off; off >>= 1) {
        if (tid < off) red[tid] += red[tid + off];
        __syncthreads();
    }
    if (tid == 0) bsum[r * NCH2 + ch] = red[0];
}

__global__ void scanB_kernel(int* __restrict__ bsum) {
    int t = threadIdx.x;
    if (t < R_) {
        int run = 0;
        for (int c = 0; c < NCH; ++c) {
            int v = bsum[t * NCH2 + c];
            bsum[t * NCH2 + c] = run;
            run += v;
        }
    }
}

__global__ void scanC_kernel(const int* __restrict__ deg, const int* __restrict__ bsum,
                             int* __restrict__ rowptr, int* __restrict__ cursor) {
    int r = blockIdx.y, ch = blockIdx.x, tid = threadIdx.x;
    int base = ch * SCAN_CHUNK + tid * 4;
    int v[4]; int s = 0;
    for (int j = 0; j < 4; ++j) {
        int i = base + j;
        v[j] = (i < N_) ? deg[r * N_ + i] : 0;
        s += v[j];
    }
    __shared__ int buf[256];
    buf[tid] = s; __syncthreads();
    for (int off = 1; off < 256; off <<= 1) {
        int t2 = (tid >= off) ? buf[tid - off] : 0;
        __syncthreads();
        buf[tid] += t2;
        __syncthreads();
    }
    int excl = buf[tid] - s + bsum[r * NCH2 + ch];
    int run = excl;
    for (int j = 0; j < 4; ++j) {
        int i = base + j;
        if (i < N_) {
            rowptr[r * (N_ + 1) + i] = run;
            cursor[r * N_ + i] = run;
            run += v[j];
        }
    }
    if (ch == 0 && tid == 0) rowptr[r * (N_ + 1) + N_] = E_;
}

__global__ void fill_kernel(const int* __restrict__ src, const int* __restrict__ dst,
                            int* __restrict__ cursor, int* __restrict__ csr_src) {
    int idx = blockIdx.x * 256 + threadIdx.x;
    if (idx < R_ * E_) {
        int r = idx / E_;
        int pos = atomicAdd(&cursor[r * N_ + dst[idx]], 1);
        csr_src[(size_t)r * E_ + pos] = src[idx];
    }
}

// ---------------- GEMM: C[r] = A @ B[r] ----------------
// A: [M,K] shared across batch, B: [R][K,Nc], C: [R][M,Nc]
// BM=64 BN=64 BK=32, 256 threads, 4x4 per thread
__global__ __launch_bounds__(256) void gemm_kernel(
        const float* __restrict__ A, const float* __restrict__ B,
        float* __restrict__ Cc, int M, int Nc, int K) {
    int r = blockIdx.z;
    const float* Br = B + (size_t)r * K * Nc;
    float* Cr = Cc + (size_t)r * M * Nc;
    __shared__ float As[32][65];
    __shared__ float Bs[32][65];
    int tid = threadIdx.x;
    int row0 = blockIdx.x * 64, col0 = blockIdx.y * 64;
    int tr = tid / 16, tc = tid % 16;
    float acc[4][4] = {};
    for (int k0 = 0; k0 < K; k0 += 32) {
        // A tile: 64x32, float4 along K
        for (int t = 0; t < 2; ++t) {
            int f = tid + t * 256;
            int i = f >> 3, jj = (f & 7) * 4;
            int gr = row0 + i, gk = k0 + jj;
            float4 v = {0.f, 0.f, 0.f, 0.f};
            if (gr < M) v = *(const float4*)(A + (size_t)gr * K + gk);
            As[jj + 0][i] = v.x; As[jj + 1][i] = v.y;
            As[jj + 2][i] = v.z; As[jj + 3][i] = v.w;
        }
        // B tile: 32x64, float4 along Nc
        for (int t = 0; t < 2; ++t) {
            int f = tid + t * 256;
            int i = f >> 4, jj = (f & 15) * 4;
            int gk = k0 + i, gc = col0 + jj;
            float4 v = {0.f, 0.f, 0.f, 0.f};
            if (gc + 3 < Nc) {
                v = *(const float4*)(Br + (size_t)gk * Nc + gc);
            } else {
                v.x = (gc + 0 < Nc) ? Br[(size_t)gk * Nc + gc + 0] : 0.f;
                v.y = (gc + 1 < Nc) ? Br[(size_t)gk * Nc + gc + 1] : 0.f;
                v.z = (gc + 2 < Nc) ? Br[(size_t)gk * Nc + gc + 2] : 0.f;
                v.w = (gc + 3 < Nc) ? Br[(size_t)gk * Nc + gc + 3] : 0.f;
            }
            Bs[i][jj + 0] = v.x; Bs[i][jj + 1] = v.y;
            Bs[i][jj + 2] = v.z; Bs[i][jj + 3] = v.w;
        }
        __syncthreads();
        #pragma unroll
        for (int k = 0; k < 32; ++k) {
            float a[4], b[4];
            #pragma unroll
            for (int u = 0; u < 4; ++u) a[u] = As[k][tr * 4 + u];
            #pragma unroll
            for (int u = 0; u < 4; ++u) b[u] = Bs[k][tc * 4 + u];
            #pragma unroll
            for (int i2 = 0; i2 < 4; ++i2)
                #pragma unroll
                for (int j2 = 0; j2 < 4; ++j2)
                    acc[i2][j2] += a[i2] * b[j2];
        }
        __syncthreads();
    }
    for (int i2 = 0; i2 < 4; ++i2) {
        int gr = row0 + tr * 4 + i2;
        if (gr >= M) continue;
        for (int j2 = 0; j2 < 4; ++j2) {
            int gc = col0 + tc * 4 + j2;
            if (gc < Nc) Cr[(size_t)gr * Nc + gc] = acc[i2][j2];
        }
    }
}

// ---------------- attention logits ----------------
// z: [R][N][H*Dd], al/ar: [R][H][Dd], el/er: [R][N][H]; one wave per (r,n)
__global__ __launch_bounds__(256) void attn_kernel(
        const float* __restrict__ z, const float* __restrict__ al,
        const float* __restrict__ ar, float* __restrict__ el,
        float* __restrict__ er, int Dd) {
    int wid = blockIdx.x * 4 + (threadIdx.x >> 6);
    int lane = threadIdx.x & 63;
    if (wid >= R_ * N_) return;
    int r = wid / N_;
    const float* zr = z + (size_t)wid * (H_ * Dd);
    for (int h = 0; h < H_; ++h) {
        float v = (lane < Dd) ? zr[h * Dd + lane] : 0.f;
        float a = (lane < Dd) ? al[(r * H_ + h) * Dd + lane] : 0.f;
        float b = (lane < Dd) ? ar[(r * H_ + h) * Dd + lane] : 0.f;
        float p = v * a, q = v * b;
        for (int off = 32; off; off >>= 1) {
            p += __shfl_xor(p, off);
            q += __shfl_xor(q, off);
        }
        if (lane == 0) {
            el[(size_t)wid * H_ + h] = p;
            er[(size_t)wid * H_ + h] = q;
        }
    }
}

// ---------------- edge softmax + aggregate ----------------
// one wave per (r,h,dst); online softmax over incoming edges; epilogue:
// +bias, optional relu, atomicAdd*(1/(H*R)) into out[n][Dd]
template <int Dd, bool RELU>
__global__ __launch_bounds__(256) void agg_kernel(
        const int* __restrict__ rowptr, const int* __restrict__ csr_src,
        const float* __restrict__ z, const float* __restrict__ el,
        const float* __restrict__ er, const float* __restrict__ bias,
        float* __restrict__ out, float scale) {
    int wid = blockIdx.x * 4 + (threadIdx.x >> 6);
    int lane = threadIdx.x & 63;
    if (wid >= R_ * H_ * N_) return;
    int n = wid % N_;
    int rh = wid / N_;
    int h = rh % H_;
    int r = rh / H_;
    int start = rowptr[r * (N_ + 1) + n];
    int end   = rowptr[r * (N_ + 1) + n + 1];
    float erv = er[((size_t)r * N_ + n) * H_ + h];
    const float* zr = z + (size_t)r * N_ * (H_ * Dd) + h * Dd;
    const int* cs = csr_src + (size_t)r * E_;
    float m = -3.0e38f, l = 0.f, acc = 0.f;
    for (int i = start; i < end; ++i) {
        int s = cs[i];
        float e = el[((size_t)r * N_ + s) * H_ + h] + erv;
        e = (e > 0.f) ? e : NEG_SLOPE * e;
        float mn = fmaxf(m, e);
        float sc = __expf(m - mn);
        float c  = __expf(e - mn);
        float zv = (lane < Dd) ? zr[(size_t)s * (H_ * Dd) + lane] : 0.f;
        l   = l * sc + c;
        acc = acc * sc + c * zv;
        m = mn;
    }
    if (lane < Dd) {
        float val = (l > 0.f) ? acc / l : 0.f;
        val += bias[r * (H_ * Dd) + h * Dd + lane];
        if (RELU) val = fmaxf(val, 0.f);
        atomicAdd(&out[(size_t)n * Dd + lane], val * scale);
    }
}

// ---------------- launch ----------------
static inline size_t align256(size_t x) { return (x + 255) & ~(size_t)255; }

extern "C" void kernel_launch(void* const* d_in, const int* in_sizes, int n_in,
                              void* d_out, int out_size, void* d_ws, size_t ws_size,
                              hipStream_t stream) {
    const float* feat = (const float*)d_in[0];
    const int*   src  = (const int*)d_in[1];
    const int*   dst  = (const int*)d_in[2];
    const float* W1   = (const float*)d_in[3];
    const float* al1  = (const float*)d_in[4];
    const float* ar1  = (const float*)d_in[5];
    const float* b1   = (const float*)d_in[6];
    const float* W2   = (const float*)d_in[7];
    const float* al2  = (const float*)d_in[8];
    const float* ar2  = (const float*)d_in[9];
    const float* b2   = (const float*)d_in[10];
    float* out = (float*)d_out;

    // workspace carve (z2 aliases z1; el2/er2 alias el1/er1)
    char* ws = (char*)d_ws;
    size_t off = 0;
    float* zbuf = (float*)(ws + off); off += align256((size_t)R_ * N_ * (H_ * HID_) * 4);
    float* el   = (float*)(ws + off); off += align256((size_t)R_ * N_ * H_ * 4);
    float* er   = (float*)(ws + off); off += align256((size_t)R_ * N_ * H_ * 4);
    float* h1   = (float*)(ws + off); off += align256((size_t)N_ * HID_ * 4);
    int* deg    = (int*)(ws + off);   off += align256((size_t)R_ * N_ * 4);
    int* rowptr = (int*)(ws + off);   off += align256((size_t)R_ * (N_ + 1) * 4);
    int* cursor = (int*)(ws + off);   off += align256((size_t)R_ * N_ * 4);
    int* bsum   = (int*)(ws + off);   off += align256((size_t)R_ * NCH2 * 4);
    int* csr    = (int*)(ws + off);   off += align256((size_t)R_ * E_ * 4);
    (void)ws_size; (void)n_in; (void)in_sizes; (void)out_size;

    const int EDGE_BLOCKS = (R_ * E_ + 255) / 256;     // 4688
    const int ROW_TILES = (N_ + 63) / 64;              // 782

    // ---- CSR build (shared by both layers) ----
    zero_kernel<<<(R_ * N_ + 255) / 256, 256, 0, stream>>>((float*)deg, (size_t)R_ * N_);
    hist_kernel<<<EDGE_BLOCKS, 256, 0, stream>>>(dst, deg);
    scanA_kernel<<<dim3(NCH, R_), 256, 0, stream>>>(deg, bsum);
    scanB_kernel<<<1, 64, 0, stream>>>(bsum);
    scanC_kernel<<<dim3(NCH, R_), 256, 0, stream>>>(deg, bsum, rowptr, cursor);
    fill_kernel<<<EDGE_BLOCKS, 256, 0, stream>>>(src, dst, cursor, csr);

    // ---- layer 1: IN->H*HID, relu ----
    gemm_kernel<<<dim3(ROW_TILES, 3, R_), 256, 0, stream>>>(feat, W1, zbuf, N_, H_ * HID_, IN_);
    attn_kernel<<<(R_ * N_) / 4, 256, 0, stream>>>(zbuf, al1, ar1, el, er, HID_);
    zero_kernel<<<((size_t)N_ * HID_ + 255) / 256, 256, 0, stream>>>(h1, (size_t)N_ * HID_);
    agg_kernel<HID_, true><<<(R_ * H_ * N_) / 4, 256, 0, stream>>>(
        rowptr, csr, zbuf, el, er, b1, h1, 1.f / (H_ * R_));

    // ---- layer 2: HID->H*C, no relu ----
    gemm_kernel<<<dim3(ROW_TILES, 2, R_), 256, 0, stream>>>(h1, W2, zbuf, N_, H_ * C_, HID_);
    attn_kernel<<<(R_ * N_) / 4, 256, 0, stream>>>(zbuf, al2, ar2, el, er, C_);
    zero_kernel<<<((size_t)N_ * C_ + 255) / 256, 256, 0, stream>>>(out, (size_t)N_ * C_);
    agg_kernel<C_, false><<<(R_ * H_ * N_) / 4, 256, 0, stream>>>(
        rowptr, csr, zbuf, el, er, b2, out, 1.f / (H_ * R_));
}

// Round 2
// 945.125 us; speedup vs baseline: 1.4844x; 1.4844x over previous
//
#include <hip/hip_runtime.h>

// Problem constants (fixed by reference)
#define R_   3
#define N_   50000
#define E_   400000
#define IN_  128
#define HID_ 64
#define C_   40
#define H_   3
#define NEG_SLOPE 0.2f

// scan chunking: 1024 elements per block (256 thr x 4)
#define SCAN_CHUNK 1024
#define NCH  49      // ceil(N_/1024)
#define NCH2 64      // padded stride

// ---------------- utility ----------------
__global__ void zero_kernel(float* __restrict__ p, size_t n) {
    size_t i = (size_t)blockIdx.x * blockDim.x + threadIdx.x;
    if (i < n) p[i] = 0.f;
}

// ---------------- CSR build ----------------
__global__ void hist_kernel(const int* __restrict__ dst, int* __restrict__ deg) {
    int idx = blockIdx.x * 256 + threadIdx.x;
    if (idx < R_ * E_) {
        int r = idx / E_;
        atomicAdd(&deg[r * N_ + dst[idx]], 1);
    }
}

__global__ void scanA_kernel(const int* __restrict__ deg, int* __restrict__ bsum) {
    int r = blockIdx.y, ch = blockIdx.x, tid = threadIdx.x;
    int base = ch * SCAN_CHUNK + tid * 4;
    int s = 0;
    for (int j = 0; j < 4; ++j) {
        int i = base + j;
        if (i < N_) s += deg[r * N_ + i];
    }
    __shared__ int red[256];
    red[tid] = s; __syncthreads();
    for (int off = 128; off; off >>= 1) {
        if (tid < off) red[tid] += red[tid + off];
        __syncthreads();
    }
    if (tid == 0) bsum[r * NCH2 + ch] = red[0];
}

__global__ void scanB_kernel(int* __restrict__ bsum) {
    int t = threadIdx.x;
    if (t < R_) {
        int run = 0;
        for (int c = 0; c < NCH; ++c) {
            int v = bsum[t * NCH2 + c];
            bsum[t * NCH2 + c] = run;
            run += v;
        }
    }
}

__global__ void scanC_kernel(const int* __restrict__ deg, const int* __restrict__ bsum,
                             int* __restrict__ rowptr, int* __restrict__ cursor) {
    int r = blockIdx.y, ch = blockIdx.x, tid = threadIdx.x;
    int base = ch * SCAN_CHUNK + tid * 4;
    int v[4]; int s = 0;
    for (int j = 0; j < 4; ++j) {
        int i = base + j;
        v[j] = (i < N_) ? deg[r * N_ + i] : 0;
        s += v[j];
    }
    __shared__ int buf[256];
    buf[tid] = s; __syncthreads();
    for (int off = 1; off < 256; off <<= 1) {
        int t2 = (tid >= off) ? buf[tid - off] : 0;
        __syncthreads();
        buf[tid] += t2;
        __syncthreads();
    }
    int excl = buf[tid] - s + bsum[r * NCH2 + ch];
    int run = excl;
    for (int j = 0; j < 4; ++j) {
        int i = base + j;
        if (i < N_) {
            rowptr[r * (N_ + 1) + i] = run;
            cursor[r * N_ + i] = run;
            run += v[j];
        }
    }
    if (ch == 0 && tid == 0) rowptr[r * (N_ + 1) + N_] = E_;
}

__global__ void fill_kernel(const int* __restrict__ src, const int* __restrict__ dst,
                            int* __restrict__ cursor, int* __restrict__ csr_src) {
    int idx = blockIdx.x * 256 + threadIdx.x;
    if (idx < R_ * E_) {
        int r = idx / E_;
        int pos = atomicAdd(&cursor[r * N_ + dst[idx]], 1);
        csr_src[(size_t)r * E_ + pos] = src[idx];
    }
}

// ---------------- GEMM: C[r] = A @ B[r] ----------------
__global__ __launch_bounds__(256) void gemm_kernel(
        const float* __restrict__ A, const float* __restrict__ B,
        float* __restrict__ Cc, int M, int Nc, int K) {
    int r = blockIdx.z;
    const float* Br = B + (size_t)r * K * Nc;
    float* Cr = Cc + (size_t)r * M * Nc;
    __shared__ float As[32][65];
    __shared__ float Bs[32][65];
    int tid = threadIdx.x;
    int row0 = blockIdx.x * 64, col0 = blockIdx.y * 64;
    int tr = tid / 16, tc = tid % 16;
    float acc[4][4] = {};
    for (int k0 = 0; k0 < K; k0 += 32) {
        for (int t = 0; t < 2; ++t) {
            int f = tid + t * 256;
            int i = f >> 3, jj = (f & 7) * 4;
            int gr = row0 + i, gk = k0 + jj;
            float4 v = {0.f, 0.f, 0.f, 0.f};
            if (gr < M) v = *(const float4*)(A + (size_t)gr * K + gk);
            As[jj + 0][i] = v.x; As[jj + 1][i] = v.y;
            As[jj + 2][i] = v.z; As[jj + 3][i] = v.w;
        }
        for (int t = 0; t < 2; ++t) {
            int f = tid + t * 256;
            int i = f >> 4, jj = (f & 15) * 4;
            int gk = k0 + i, gc = col0 + jj;
            float4 v = {0.f, 0.f, 0.f, 0.f};
            if (gc + 3 < Nc) {
                v = *(const float4*)(Br + (size_t)gk * Nc + gc);
            } else {
                v.x = (gc + 0 < Nc) ? Br[(size_t)gk * Nc + gc + 0] : 0.f;
                v.y = (gc + 1 < Nc) ? Br[(size_t)gk * Nc + gc + 1] : 0.f;
                v.z = (gc + 2 < Nc) ? Br[(size_t)gk * Nc + gc + 2] : 0.f;
                v.w = (gc + 3 < Nc) ? Br[(size_t)gk * Nc + gc + 3] : 0.f;
            }
            Bs[i][jj + 0] = v.x; Bs[i][jj + 1] = v.y;
            Bs[i][jj + 2] = v.z; Bs[i][jj + 3] = v.w;
        }
        __syncthreads();
        #pragma unroll
        for (int k = 0; k < 32; ++k) {
            float a[4], b[4];
            #pragma unroll
            for (int u = 0; u < 4; ++u) a[u] = As[k][tr * 4 + u];
            #pragma unroll
            for (int u = 0; u < 4; ++u) b[u] = Bs[k][tc * 4 + u];
            #pragma unroll
            for (int i2 = 0; i2 < 4; ++i2)
                #pragma unroll
                for (int j2 = 0; j2 < 4; ++j2)
                    acc[i2][j2] += a[i2] * b[j2];
        }
        __syncthreads();
    }
    for (int i2 = 0; i2 < 4; ++i2) {
        int gr = row0 + tr * 4 + i2;
        if (gr >= M) continue;
        for (int j2 = 0; j2 < 4; ++j2) {
            int gc = col0 + tc * 4 + j2;
            if (gc < Nc) Cr[(size_t)gr * Nc + gc] = acc[i2][j2];
        }
    }
}

// ---------------- attention logits ----------------
// z: [R][N][H*Dd], al/ar: [R][H][Dd], el/er: [R][N][H]; one wave per (r,n)
__global__ __launch_bounds__(256) void attn_kernel(
        const float* __restrict__ z, const float* __restrict__ al,
        const float* __restrict__ ar, float* __restrict__ el,
        float* __restrict__ er, int Dd) {
    int wid = blockIdx.x * 4 + (threadIdx.x >> 6);
    int lane = threadIdx.x & 63;
    if (wid >= R_ * N_) return;
    int r = wid / N_;
    const float* zr = z + (size_t)wid * (H_ * Dd);
    for (int h = 0; h < H_; ++h) {
        float v = (lane < Dd) ? zr[h * Dd + lane] : 0.f;
        float a = (lane < Dd) ? al[(r * H_ + h) * Dd + lane] : 0.f;
        float b = (lane < Dd) ? ar[(r * H_ + h) * Dd + lane] : 0.f;
        float p = v * a, q = v * b;
        for (int off = 32; off; off >>= 1) {
            p += __shfl_xor(p, off);
            q += __shfl_xor(q, off);
        }
        if (lane == 0) {
            el[(size_t)wid * H_ + h] = p;
            er[(size_t)wid * H_ + h] = q;
        }
    }
}

// ---------------- softmax coefficients (decoupled from gather) ----------------
// one THREAD per (r,n): walk CSR row twice over el/er scalars only (L2-resident),
// write per-edge unnormalized c = exp(e - m) into ebuf[(r*E+i)*4 + h], and
// per-(r,n,h) 1/l into linv.
__global__ __launch_bounds__(256) void coeff_kernel(
        const int* __restrict__ rowptr, const int* __restrict__ csr_src,
        const float* __restrict__ el, const float* __restrict__ er,
        float* __restrict__ ebuf, float* __restrict__ linv) {
    int idx = blockIdx.x * 256 + threadIdx.x;
    if (idx >= R_ * N_) return;
    int r = idx / N_, n = idx - r * N_;
    int start = rowptr[r * (N_ + 1) + n];
    int end   = rowptr[r * (N_ + 1) + n + 1];
    const int* cs = csr_src + (size_t)r * E_;
    const float* elr = el + (size_t)r * N_ * H_;
    float* eb = ebuf + (size_t)r * E_ * 4;
    float ev0 = er[idx * H_ + 0], ev1 = er[idx * H_ + 1], ev2 = er[idx * H_ + 2];
    float m0 = -3.0e38f, m1 = -3.0e38f, m2 = -3.0e38f;
    for (int i = start; i < end; ++i) {
        int s = cs[i];
        float e0 = elr[s * H_ + 0] + ev0; e0 = (e0 > 0.f) ? e0 : NEG_SLOPE * e0;
        float e1 = elr[s * H_ + 1] + ev1; e1 = (e1 > 0.f) ? e1 : NEG_SLOPE * e1;
        float e2 = elr[s * H_ + 2] + ev2; e2 = (e2 > 0.f) ? e2 : NEG_SLOPE * e2;
        eb[i * 4 + 0] = e0; eb[i * 4 + 1] = e1; eb[i * 4 + 2] = e2;
        m0 = fmaxf(m0, e0); m1 = fmaxf(m1, e1); m2 = fmaxf(m2, e2);
    }
    float l0 = 0.f, l1 = 0.f, l2 = 0.f;
    for (int i = start; i < end; ++i) {
        float c0 = __expf(eb[i * 4 + 0] - m0);
        float c1 = __expf(eb[i * 4 + 1] - m1);
        float c2 = __expf(eb[i * 4 + 2] - m2);
        eb[i * 4 + 0] = c0; eb[i * 4 + 1] = c1; eb[i * 4 + 2] = c2;
        l0 += c0; l1 += c1; l2 += c2;
    }
    linv[idx * H_ + 0] = (l0 > 0.f) ? 1.f / l0 : 0.f;
    linv[idx * H_ + 1] = (l1 > 0.f) ? 1.f / l1 : 0.f;
    linv[idx * H_ + 2] = (l2 > 0.f) ? 1.f / l2 : 0.f;
}

// ---------------- gather + aggregate (all 3 heads per wave) ----------------
// one wave per (r,dst); lanes = output dims; per edge: 1 csr load, 1 float4
// coeff broadcast, 3 coalesced z-slice loads, 3 independent FMA chains.
// Epilogue: *1/l, +bias, optional relu, head-mean, one atomicAdd*(1/(H*R)).
template <int Dd, bool RELU>
__global__ __launch_bounds__(256) void agg2_kernel(
        const int* __restrict__ rowptr, const int* __restrict__ csr_src,
        const float* __restrict__ z, const float* __restrict__ ebuf,
        const float* __restrict__ linv, const float* __restrict__ bias,
        float* __restrict__ out, float scale) {
    int wid = blockIdx.x * 4 + (threadIdx.x >> 6);
    int lane = threadIdx.x & 63;
    if (wid >= R_ * N_) return;
    int r = wid / N_, n = wid - r * N_;
    int start = rowptr[r * (N_ + 1) + n];
    int end   = rowptr[r * (N_ + 1) + n + 1];
    const int* cs = csr_src + (size_t)r * E_;
    const float4* eb = (const float4*)(ebuf + (size_t)r * E_ * 4);
    const float* zr = z + (size_t)r * N_ * (H_ * Dd);
    float a0 = 0.f, a1 = 0.f, a2 = 0.f;
    for (int i = start; i < end; ++i) {
        int s = cs[i];
        float4 c = eb[i];
        const float* zrow = zr + (size_t)s * (H_ * Dd);
        float zv0 = 0.f, zv1 = 0.f, zv2 = 0.f;
        if (lane < Dd) {
            zv0 = zrow[lane];
            zv1 = zrow[Dd + lane];
            zv2 = zrow[2 * Dd + lane];
        }
        a0 += c.x * zv0;
        a1 += c.y * zv1;
        a2 += c.z * zv2;
    }
    if (lane < Dd) {
        float li0 = linv[wid * H_ + 0];
        float li1 = linv[wid * H_ + 1];
        float li2 = linv[wid * H_ + 2];
        const float* br = bias + r * (H_ * Dd);
        float v0 = a0 * li0 + br[0 * Dd + lane];
        float v1 = a1 * li1 + br[1 * Dd + lane];
        float v2 = a2 * li2 + br[2 * Dd + lane];
        if (RELU) {
            v0 = fmaxf(v0, 0.f); v1 = fmaxf(v1, 0.f); v2 = fmaxf(v2, 0.f);
        }
        atomicAdd(&out[(size_t)n * Dd + lane], (v0 + v1 + v2) * scale);
    }
}

// ---------------- launch ----------------
static inline size_t align256(size_t x) { return (x + 255) & ~(size_t)255; }

extern "C" void kernel_launch(void* const* d_in, const int* in_sizes, int n_in,
                              void* d_out, int out_size, void* d_ws, size_t ws_size,
                              hipStream_t stream) {
    const float* feat = (const float*)d_in[0];
    const int*   src  = (const int*)d_in[1];
    const int*   dst  = (const int*)d_in[2];
    const float* W1   = (const float*)d_in[3];
    const float* al1  = (const float*)d_in[4];
    const float* ar1  = (const float*)d_in[5];
    const float* b1   = (const float*)d_in[6];
    const float* W2   = (const float*)d_in[7];
    const float* al2  = (const float*)d_in[8];
    const float* ar2  = (const float*)d_in[9];
    const float* b2   = (const float*)d_in[10];
    float* out = (float*)d_out;

    // workspace carve
    char* ws = (char*)d_ws;
    size_t off = 0;
    float* zbuf = (float*)(ws + off); off += align256((size_t)R_ * N_ * (H_ * HID_) * 4);
    float* el   = (float*)(ws + off); off += align256((size_t)R_ * N_ * H_ * 4);
    float* er   = (float*)(ws + off); off += align256((size_t)R_ * N_ * H_ * 4);
    float* h1   = (float*)(ws + off); off += align256((size_t)N_ * HID_ * 4);
    int* deg    = (int*)(ws + off);   off += align256((size_t)R_ * N_ * 4);
    int* rowptr = (int*)(ws + off);   off += align256((size_t)R_ * (N_ + 1) * 4);
    int* cursor = (int*)(ws + off);   off += align256((size_t)R_ * N_ * 4);
    int* bsum   = (int*)(ws + off);   off += align256((size_t)R_ * NCH2 * 4);
    int* csr    = (int*)(ws + off);   off += align256((size_t)R_ * E_ * 4);
    float* ebuf = (float*)(ws + off); off += align256((size_t)R_ * E_ * 4 * 4);
    float* linv = (float*)(ws + off); off += align256((size_t)R_ * N_ * H_ * 4);
    (void)ws_size; (void)n_in; (void)in_sizes; (void)out_size;

    const int EDGE_BLOCKS = (R_ * E_ + 255) / 256;     // 4688
    const int ROW_TILES = (N_ + 63) / 64;              // 782
    const int NODE_BLOCKS = (R_ * N_ + 255) / 256;     // 586
    const int WAVE_BLOCKS = (R_ * N_) / 4;             // 37500

    // ---- CSR build (shared by both layers) ----
    zero_kernel<<<NODE_BLOCKS, 256, 0, stream>>>((float*)deg, (size_t)R_ * N_);
    hist_kernel<<<EDGE_BLOCKS, 256, 0, stream>>>(dst, deg);
    scanA_kernel<<<dim3(NCH, R_), 256, 0, stream>>>(deg, bsum);
    scanB_kernel<<<1, 64, 0, stream>>>(bsum);
    scanC_kernel<<<dim3(NCH, R_), 256, 0, stream>>>(deg, bsum, rowptr, cursor);
    fill_kernel<<<EDGE_BLOCKS, 256, 0, stream>>>(src, dst, cursor, csr);

    // ---- layer 1: IN->H*HID, relu ----
    gemm_kernel<<<dim3(ROW_TILES, 3, R_), 256, 0, stream>>>(feat, W1, zbuf, N_, H_ * HID_, IN_);
    attn_kernel<<<WAVE_BLOCKS, 256, 0, stream>>>(zbuf, al1, ar1, el, er, HID_);
    coeff_kernel<<<NODE_BLOCKS, 256, 0, stream>>>(rowptr, csr, el, er, ebuf, linv);
    zero_kernel<<<((size_t)N_ * HID_ + 255) / 256, 256, 0, stream>>>(h1, (size_t)N_ * HID_);
    agg2_kernel<HID_, true><<<WAVE_BLOCKS, 256, 0, stream>>>(
        rowptr, csr, zbuf, ebuf, linv, b1, h1, 1.f / (H_ * R_));

    // ---- layer 2: HID->H*C, no relu ----
    gemm_kernel<<<dim3(ROW_TILES, 2, R_), 256, 0, stream>>>(h1, W2, zbuf, N_, H_ * C_, HID_);
    attn_kernel<<<WAVE_BLOCKS, 256, 0, stream>>>(zbuf, al2, ar2, el, er, C_);
    coeff_kernel<<<NODE_BLOCKS, 256, 0, stream>>>(rowptr, csr, el, er, ebuf, linv);
    zero_kernel<<<((size_t)N_ * C_ + 255) / 256, 256, 0, stream>>>(out, (size_t)N_ * C_);
    agg2_kernel<C_, false><<<WAVE_BLOCKS, 256, 0, stream>>>(
        rowptr, csr, zbuf, ebuf, linv, b2, out, 1.f / (H_ * R_));
}

// Round 3
// 843.382 us; speedup vs baseline: 1.6634x; 1.1206x over previous
//
#include <hip/hip_runtime.h>

// Problem constants (fixed by reference)
#define R_   3
#define N_   50000
#define E_   400000
#define IN_  128
#define HID_ 64
#define C_   40
#define H_   3
#define NEG_SLOPE 0.2f

#define SCAN_CHUNK 1024
#define NCH  49      // ceil(N_/1024)
#define NCH2 64      // padded stride

typedef _Float16 half_t;
typedef _Float16 f16x8 __attribute__((ext_vector_type(8)));
typedef _Float16 f16x4 __attribute__((ext_vector_type(4)));
typedef float float4v __attribute__((ext_vector_type(4)));

// ---------------- utility ----------------
__global__ void zero_kernel(float* __restrict__ p, size_t n) {
    size_t i = (size_t)blockIdx.x * blockDim.x + threadIdx.x;
    if (i < n) p[i] = 0.f;
}

// float -> half, vectorized x4 (n must be divisible by 4)
__global__ void cast_f2h_kernel(const float* __restrict__ in, half_t* __restrict__ outp, int n4) {
    int i = blockIdx.x * 256 + threadIdx.x;
    if (i < n4) {
        float4 v = ((const float4*)in)[i];
        f16x4 h;
        h[0] = (half_t)v.x; h[1] = (half_t)v.y;
        h[2] = (half_t)v.z; h[3] = (half_t)v.w;
        ((f16x4*)outp)[i] = h;
    }
}

// W: [R][K][Nc] fp32 -> Wt: [R][Nc][K] fp16 (tiny matrices)
__global__ void transcast_kernel(const float* __restrict__ W, half_t* __restrict__ Wt,
                                 int K, int Nc) {
    int idx = blockIdx.x * 256 + threadIdx.x;
    int total = R_ * K * Nc;
    if (idx < total) {
        int r = idx / (K * Nc);
        int rem = idx - r * K * Nc;
        int n = rem / K;
        int k = rem - n * K;
        Wt[idx] = (half_t)W[((size_t)r * K + k) * Nc + n];
    }
}

// ---------------- CSR build ----------------
__global__ void hist_kernel(const int* __restrict__ dst, int* __restrict__ deg) {
    int idx = blockIdx.x * 256 + threadIdx.x;
    if (idx < R_ * E_) {
        int r = idx / E_;
        atomicAdd(&deg[r * N_ + dst[idx]], 1);
    }
}

__global__ void scanA_kernel(const int* __restrict__ deg, int* __restrict__ bsum) {
    int r = blockIdx.y, ch = blockIdx.x, tid = threadIdx.x;
    int base = ch * SCAN_CHUNK + tid * 4;
    int s = 0;
    for (int j = 0; j < 4; ++j) {
        int i = base + j;
        if (i < N_) s += deg[r * N_ + i];
    }
    __shared__ int red[256];
    red[tid] = s; __syncthreads();
    for (int off = 128; off; off >>= 1) {
        if (tid < off) red[tid] += red[tid + off];
        __syncthreads();
    }
    if (tid == 0) bsum[r * NCH2 + ch] = red[0];
}

__global__ void scanB_kernel(int* __restrict__ bsum) {
    int t = threadIdx.x;
    if (t < R_) {
        int run = 0;
        for (int c = 0; c < NCH; ++c) {
            int v = bsum[t * NCH2 + c];
            bsum[t * NCH2 + c] = run;
            run += v;
        }
    }
}

__global__ void scanC_kernel(const int* __restrict__ deg, const int* __restrict__ bsum,
                             int* __restrict__ rowptr, int* __restrict__ cursor) {
    int r = blockIdx.y, ch = blockIdx.x, tid = threadIdx.x;
    int base = ch * SCAN_CHUNK + tid * 4;
    int v[4]; int s = 0;
    for (int j = 0; j < 4; ++j) {
        int i = base + j;
        v[j] = (i < N_) ? deg[r * N_ + i] : 0;
        s += v[j];
    }
    __shared__ int buf[256];
    buf[tid] = s; __syncthreads();
    for (int off = 1; off < 256; off <<= 1) {
        int t2 = (tid >= off) ? buf[tid - off] : 0;
        __syncthreads();
        buf[tid] += t2;
        __syncthreads();
    }
    int excl = buf[tid] - s + bsum[r * NCH2 + ch];
    int run = excl;
    for (int j = 0; j < 4; ++j) {
        int i = base + j;
        if (i < N_) {
            rowptr[r * (N_ + 1) + i] = run;
            cursor[r * N_ + i] = run;
            run += v[j];
        }
    }
    if (ch == 0 && tid == 0) rowptr[r * (N_ + 1) + N_] = E_;
}

__global__ void fill_kernel(const int* __restrict__ src, const int* __restrict__ dst,
                            int* __restrict__ cursor, int* __restrict__ csr_src) {
    int idx = blockIdx.x * 256 + threadIdx.x;
    if (idx < R_ * E_) {
        int r = idx / E_;
        int pos = atomicAdd(&cursor[r * N_ + dst[idx]], 1);
        csr_src[(size_t)r * E_ + pos] = src[idx];
    }
}

// ---------------- MFMA GEMM: Z[r] = A @ Bt[r]^T ----------------
// A: [M][K] fp16; Bt: [R][Nc][K] fp16 (pre-transposed); Z: [R][M][Nc] fp16.
// Block = 4 waves; wave computes 16 rows x 64 cols via 4 mfma_f32_16x16x32_f16
// accumulators. A frags: direct global 16B/lane (16 full cache lines/wave).
// B frags: direct global from Bt (tiny, L1/L2-resident). No LDS at all.
template <int K>
__global__ __launch_bounds__(256) void mfma_gemm_kernel(
        const half_t* __restrict__ A, const half_t* __restrict__ Bt,
        half_t* __restrict__ Z, int M, int Nc) {
    int r = blockIdx.z;
    int wave = threadIdx.x >> 6, lane = threadIdx.x & 63;
    int lrow = lane & 15, lq = lane >> 4;       // quad = lane>>4
    int rowA = blockIdx.x * 64 + wave * 16 + lrow;
    int col0 = blockIdx.y * 64;
    const half_t* Btr = Bt + (size_t)r * Nc * K;
    const half_t* aP = A + (size_t)rowA * K + lq * 8;
    bool arow_ok = (rowA < M);
    f16x8 zv8 = {};
    float4v acc[4] = {};
    #pragma unroll
    for (int k0 = 0; k0 < K; k0 += 32) {
        // A[m=lane&15][k = lq*8 + j]
        f16x8 af = arow_ok ? *(const f16x8*)(aP + k0) : zv8;
        #pragma unroll
        for (int ct = 0; ct < 4; ++ct) {
            int col = col0 + ct * 16 + lrow;
            // B[k = lq*8 + j][n = lane&15] == Bt[n][k]
            f16x8 bf = (col < Nc) ? *(const f16x8*)(Btr + (size_t)col * K + lq * 8 + k0) : zv8;
            acc[ct] = __builtin_amdgcn_mfma_f32_16x16x32_f16(af, bf, acc[ct], 0, 0, 0);
        }
    }
    // C/D layout: col = lane&15, row = (lane>>4)*4 + reg
    half_t* Zr = Z + (size_t)r * M * Nc;
    int rbase = blockIdx.x * 64 + wave * 16 + lq * 4;
    #pragma unroll
    for (int ct = 0; ct < 4; ++ct) {
        int col = col0 + ct * 16 + lrow;
        if (col >= Nc) continue;
        #pragma unroll
        for (int g = 0; g < 4; ++g) {
            int row = rbase + g;
            if (row < M) Zr[(size_t)row * Nc + col] = (half_t)acc[ct][g];
        }
    }
}

// ---------------- attention logits ----------------
// z: [R][N][H*Dd] fp16; al/ar fp32; el/er: [R][N][H] fp32; one wave per (r,n)
__global__ __launch_bounds__(256) void attn_kernel(
        const half_t* __restrict__ z, const float* __restrict__ al,
        const float* __restrict__ ar, float* __restrict__ el,
        float* __restrict__ er, int Dd) {
    int wid = blockIdx.x * 4 + (threadIdx.x >> 6);
    int lane = threadIdx.x & 63;
    if (wid >= R_ * N_) return;
    int r = wid / N_;
    const half_t* zr = z + (size_t)wid * (H_ * Dd);
    for (int h = 0; h < H_; ++h) {
        float v = (lane < Dd) ? (float)zr[h * Dd + lane] : 0.f;
        float a = (lane < Dd) ? al[(r * H_ + h) * Dd + lane] : 0.f;
        float b = (lane < Dd) ? ar[(r * H_ + h) * Dd + lane] : 0.f;
        float p = v * a, q = v * b;
        for (int off = 32; off; off >>= 1) {
            p += __shfl_xor(p, off);
            q += __shfl_xor(q, off);
        }
        if (lane == 0) {
            el[(size_t)wid * H_ + h] = p;
            er[(size_t)wid * H_ + h] = q;
        }
    }
}

// ---------------- softmax coefficients ----------------
__global__ __launch_bounds__(256) void coeff_kernel(
        const int* __restrict__ rowptr, const int* __restrict__ csr_src,
        const float* __restrict__ el, const float* __restrict__ er,
        float* __restrict__ ebuf, float* __restrict__ linv) {
    int idx = blockIdx.x * 256 + threadIdx.x;
    if (idx >= R_ * N_) return;
    int r = idx / N_, n = idx - r * N_;
    int start = rowptr[r * (N_ + 1) + n];
    int end   = rowptr[r * (N_ + 1) + n + 1];
    const int* cs = csr_src + (size_t)r * E_;
    const float* elr = el + (size_t)r * N_ * H_;
    float* eb = ebuf + (size_t)r * E_ * 4;
    float ev0 = er[idx * H_ + 0], ev1 = er[idx * H_ + 1], ev2 = er[idx * H_ + 2];
    float m0 = -3.0e38f, m1 = -3.0e38f, m2 = -3.0e38f;
    for (int i = start; i < end; ++i) {
        int s = cs[i];
        float e0 = elr[s * H_ + 0] + ev0; e0 = (e0 > 0.f) ? e0 : NEG_SLOPE * e0;
        float e1 = elr[s * H_ + 1] + ev1; e1 = (e1 > 0.f) ? e1 : NEG_SLOPE * e1;
        float e2 = elr[s * H_ + 2] + ev2; e2 = (e2 > 0.f) ? e2 : NEG_SLOPE * e2;
        eb[i * 4 + 0] = e0; eb[i * 4 + 1] = e1; eb[i * 4 + 2] = e2;
        m0 = fmaxf(m0, e0); m1 = fmaxf(m1, e1); m2 = fmaxf(m2, e2);
    }
    float l0 = 0.f, l1 = 0.f, l2 = 0.f;
    for (int i = start; i < end; ++i) {
        float c0 = __expf(eb[i * 4 + 0] - m0);
        float c1 = __expf(eb[i * 4 + 1] - m1);
        float c2 = __expf(eb[i * 4 + 2] - m2);
        eb[i * 4 + 0] = c0; eb[i * 4 + 1] = c1; eb[i * 4 + 2] = c2;
        l0 += c0; l1 += c1; l2 += c2;
    }
    linv[idx * H_ + 0] = (l0 > 0.f) ? 1.f / l0 : 0.f;
    linv[idx * H_ + 1] = (l1 > 0.f) ? 1.f / l1 : 0.f;
    linv[idx * H_ + 2] = (l2 > 0.f) ? 1.f / l2 : 0.f;
}

// ---------------- gather + aggregate (fp16 z, all 3 heads per wave) ----------------
template <int Dd, bool RELU>
__global__ __launch_bounds__(256) void agg2_kernel(
        const int* __restrict__ rowptr, const int* __restrict__ csr_src,
        const half_t* __restrict__ z, const float* __restrict__ ebuf,
        const float* __restrict__ linv, const float* __restrict__ bias,
        float* __restrict__ out, float scale) {
    int wid = blockIdx.x * 4 + (threadIdx.x >> 6);
    int lane = threadIdx.x & 63;
    if (wid >= R_ * N_) return;
    int r = wid / N_, n = wid - r * N_;
    int start = rowptr[r * (N_ + 1) + n];
    int end   = rowptr[r * (N_ + 1) + n + 1];
    const int* cs = csr_src + (size_t)r * E_;
    const float4* eb = (const float4*)(ebuf + (size_t)r * E_ * 4);
    const half_t* zr = z + (size_t)r * N_ * (H_ * Dd);
    float a0 = 0.f, a1 = 0.f, a2 = 0.f;
    for (int i = start; i < end; ++i) {
        int s = cs[i];
        float4 c = eb[i];
        const half_t* zrow = zr + (size_t)s * (H_ * Dd);
        float zv0 = 0.f, zv1 = 0.f, zv2 = 0.f;
        if (lane < Dd) {
            zv0 = (float)zrow[lane];
            zv1 = (float)zrow[Dd + lane];
            zv2 = (float)zrow[2 * Dd + lane];
        }
        a0 += c.x * zv0;
        a1 += c.y * zv1;
        a2 += c.z * zv2;
    }
    if (lane < Dd) {
        float li0 = linv[wid * H_ + 0];
        float li1 = linv[wid * H_ + 1];
        float li2 = linv[wid * H_ + 2];
        const float* br = bias + r * (H_ * Dd);
        float v0 = a0 * li0 + br[0 * Dd + lane];
        float v1 = a1 * li1 + br[1 * Dd + lane];
        float v2 = a2 * li2 + br[2 * Dd + lane];
        if (RELU) {
            v0 = fmaxf(v0, 0.f); v1 = fmaxf(v1, 0.f); v2 = fmaxf(v2, 0.f);
        }
        atomicAdd(&out[(size_t)n * Dd + lane], (v0 + v1 + v2) * scale);
    }
}

// ---------------- launch ----------------
static inline size_t align256(size_t x) { return (x + 255) & ~(size_t)255; }

extern "C" void kernel_launch(void* const* d_in, const int* in_sizes, int n_in,
                              void* d_out, int out_size, void* d_ws, size_t ws_size,
                              hipStream_t stream) {
    const float* feat = (const float*)d_in[0];
    const int*   src  = (const int*)d_in[1];
    const int*   dst  = (const int*)d_in[2];
    const float* W1   = (const float*)d_in[3];
    const float* al1  = (const float*)d_in[4];
    const float* ar1  = (const float*)d_in[5];
    const float* b1   = (const float*)d_in[6];
    const float* W2   = (const float*)d_in[7];
    const float* al2  = (const float*)d_in[8];
    const float* ar2  = (const float*)d_in[9];
    const float* b2   = (const float*)d_in[10];
    float* out = (float*)d_out;

    // workspace carve
    char* ws = (char*)d_ws;
    size_t off = 0;
    half_t* zbuf = (half_t*)(ws + off); off += align256((size_t)R_ * N_ * (H_ * HID_) * 2);
    half_t* featH = (half_t*)(ws + off); off += align256((size_t)N_ * IN_ * 2);
    half_t* h1h  = (half_t*)(ws + off); off += align256((size_t)N_ * HID_ * 2);
    half_t* W1t  = (half_t*)(ws + off); off += align256((size_t)R_ * (H_ * HID_) * IN_ * 2);
    half_t* W2t  = (half_t*)(ws + off); off += align256((size_t)R_ * (H_ * C_) * HID_ * 2);
    float* el   = (float*)(ws + off); off += align256((size_t)R_ * N_ * H_ * 4);
    float* er   = (float*)(ws + off); off += align256((size_t)R_ * N_ * H_ * 4);
    float* h1f  = (float*)(ws + off); off += align256((size_t)N_ * HID_ * 4);
    int* deg    = (int*)(ws + off);   off += align256((size_t)R_ * N_ * 4);
    int* rowptr = (int*)(ws + off);   off += align256((size_t)R_ * (N_ + 1) * 4);
    int* cursor = (int*)(ws + off);   off += align256((size_t)R_ * N_ * 4);
    int* bsum   = (int*)(ws + off);   off += align256((size_t)R_ * NCH2 * 4);
    int* csr    = (int*)(ws + off);   off += align256((size_t)R_ * E_ * 4);
    float* ebuf = (float*)(ws + off); off += align256((size_t)R_ * E_ * 4 * 4);
    float* linv = (float*)(ws + off); off += align256((size_t)R_ * N_ * H_ * 4);
    (void)ws_size; (void)n_in; (void)in_sizes; (void)out_size;

    const int EDGE_BLOCKS = (R_ * E_ + 255) / 256;     // 4688
    const int ROW_TILES = (N_ + 63) / 64;              // 782
    const int NODE_BLOCKS = (R_ * N_ + 255) / 256;     // 586
    const int WAVE_BLOCKS = (R_ * N_) / 4;             // 37500

    // ---- input casts / weight transposes ----
    cast_f2h_kernel<<<(N_ * IN_ / 4 + 255) / 256, 256, 0, stream>>>(feat, featH, N_ * IN_ / 4);
    transcast_kernel<<<(R_ * IN_ * (H_ * HID_) + 255) / 256, 256, 0, stream>>>(W1, W1t, IN_, H_ * HID_);
    transcast_kernel<<<(R_ * HID_ * (H_ * C_) + 255) / 256, 256, 0, stream>>>(W2, W2t, HID_, H_ * C_);

    // ---- CSR build (shared by both layers) ----
    zero_kernel<<<NODE_BLOCKS, 256, 0, stream>>>((float*)deg, (size_t)R_ * N_);
    hist_kernel<<<EDGE_BLOCKS, 256, 0, stream>>>(dst, deg);
    scanA_kernel<<<dim3(NCH, R_), 256, 0, stream>>>(deg, bsum);
    scanB_kernel<<<1, 64, 0, stream>>>(bsum);
    scanC_kernel<<<dim3(NCH, R_), 256, 0, stream>>>(deg, bsum, rowptr, cursor);
    fill_kernel<<<EDGE_BLOCKS, 256, 0, stream>>>(src, dst, cursor, csr);

    // ---- layer 1: IN -> H*HID, relu ----
    mfma_gemm_kernel<IN_><<<dim3(ROW_TILES, 3, R_), 256, 0, stream>>>(
        featH, W1t, zbuf, N_, H_ * HID_);
    attn_kernel<<<WAVE_BLOCKS, 256, 0, stream>>>(zbuf, al1, ar1, el, er, HID_);
    coeff_kernel<<<NODE_BLOCKS, 256, 0, stream>>>(rowptr, csr, el, er, ebuf, linv);
    zero_kernel<<<((size_t)N_ * HID_ + 255) / 256, 256, 0, stream>>>(h1f, (size_t)N_ * HID_);
    agg2_kernel<HID_, true><<<WAVE_BLOCKS, 256, 0, stream>>>(
        rowptr, csr, zbuf, ebuf, linv, b1, h1f, 1.f / (H_ * R_));
    cast_f2h_kernel<<<(N_ * HID_ / 4 + 255) / 256, 256, 0, stream>>>(h1f, h1h, N_ * HID_ / 4);

    // ---- layer 2: HID -> H*C, no relu ----
    mfma_gemm_kernel<HID_><<<dim3(ROW_TILES, 2, R_), 256, 0, stream>>>(
        h1h, W2t, zbuf, N_, H_ * C_);
    attn_kernel<<<WAVE_BLOCKS, 256, 0, stream>>>(zbuf, al2, ar2, el, er, C_);
    coeff_kernel<<<NODE_BLOCKS, 256, 0, stream>>>(rowptr, csr, el, er, ebuf, linv);
    zero_kernel<<<((size_t)N_ * C_ + 255) / 256, 256, 0, stream>>>(out, (size_t)N_ * C_);
    agg2_kernel<C_, false><<<WAVE_BLOCKS, 256, 0, stream>>>(
        rowptr, csr, zbuf, ebuf, linv, b2, out, 1.f / (H_ * R_));
}

// Round 4
// 828.271 us; speedup vs baseline: 1.6938x; 1.0182x over previous
//
#include <hip/hip_runtime.h>

// Problem constants (fixed by reference)
#define R_   3
#define N_   50000
#define E_   400000
#define IN_  128
#define HID_ 64
#define C_   40
#define H_   3
#define NEG_SLOPE 0.2f

#define SCAN_CHUNK 1024
#define NCH  49      // ceil(N_/1024)
#define NCH2 64      // padded stride

typedef _Float16 half_t;
typedef _Float16 f16x8 __attribute__((ext_vector_type(8)));
typedef _Float16 f16x4 __attribute__((ext_vector_type(4)));
typedef float float4v __attribute__((ext_vector_type(4)));

// ---------------- utility ----------------
__global__ void zero_kernel(float* __restrict__ p, size_t n) {
    size_t i = (size_t)blockIdx.x * blockDim.x + threadIdx.x;
    if (i < n) p[i] = 0.f;
}

// float -> half, vectorized x4 (n must be divisible by 4)
__global__ void cast_f2h_kernel(const float* __restrict__ in, half_t* __restrict__ outp, int n4) {
    int i = blockIdx.x * 256 + threadIdx.x;
    if (i < n4) {
        float4 v = ((const float4*)in)[i];
        f16x4 h;
        h[0] = (half_t)v.x; h[1] = (half_t)v.y;
        h[2] = (half_t)v.z; h[3] = (half_t)v.w;
        ((f16x4*)outp)[i] = h;
    }
}

// W: [R][K][Nc] fp32 -> Wt: [R][Nc][K] fp16 (tiny matrices)
__global__ void transcast_kernel(const float* __restrict__ W, half_t* __restrict__ Wt,
                                 int K, int Nc) {
    int idx = blockIdx.x * 256 + threadIdx.x;
    int total = R_ * K * Nc;
    if (idx < total) {
        int r = idx / (K * Nc);
        int rem = idx - r * K * Nc;
        int n = rem / K;
        int k = rem - n * K;
        Wt[idx] = (half_t)W[((size_t)r * K + k) * Nc + n];
    }
}

// ---------------- CSR build ----------------
__global__ void hist_kernel(const int* __restrict__ dst, int* __restrict__ deg) {
    int idx = blockIdx.x * 256 + threadIdx.x;
    if (idx < R_ * E_) {
        int r = idx / E_;
        atomicAdd(&deg[r * N_ + dst[idx]], 1);
    }
}

__global__ void scanA_kernel(const int* __restrict__ deg, int* __restrict__ bsum) {
    int r = blockIdx.y, ch = blockIdx.x, tid = threadIdx.x;
    int base = ch * SCAN_CHUNK + tid * 4;
    int s = 0;
    for (int j = 0; j < 4; ++j) {
        int i = base + j;
        if (i < N_) s += deg[r * N_ + i];
    }
    __shared__ int red[256];
    red[tid] = s; __syncthreads();
    for (int off = 128; off; off >>= 1) {
        if (tid < off) red[tid] += red[tid + off];
        __syncthreads();
    }
    if (tid == 0) bsum[r * NCH2 + ch] = red[0];
}

__global__ void scanB_kernel(int* __restrict__ bsum) {
    int t = threadIdx.x;
    if (t < R_) {
        int run = 0;
        for (int c = 0; c < NCH; ++c) {
            int v = bsum[t * NCH2 + c];
            bsum[t * NCH2 + c] = run;
            run += v;
        }
    }
}

__global__ void scanC_kernel(const int* __restrict__ deg, const int* __restrict__ bsum,
                             int* __restrict__ rowptr, int* __restrict__ cursor) {
    int r = blockIdx.y, ch = blockIdx.x, tid = threadIdx.x;
    int base = ch * SCAN_CHUNK + tid * 4;
    int v[4]; int s = 0;
    for (int j = 0; j < 4; ++j) {
        int i = base + j;
        v[j] = (i < N_) ? deg[r * N_ + i] : 0;
        s += v[j];
    }
    __shared__ int buf[256];
    buf[tid] = s; __syncthreads();
    for (int off = 1; off < 256; off <<= 1) {
        int t2 = (tid >= off) ? buf[tid - off] : 0;
        __syncthreads();
        buf[tid] += t2;
        __syncthreads();
    }
    int excl = buf[tid] - s + bsum[r * NCH2 + ch];
    int run = excl;
    for (int j = 0; j < 4; ++j) {
        int i = base + j;
        if (i < N_) {
            rowptr[r * (N_ + 1) + i] = run;
            cursor[r * N_ + i] = run;
            run += v[j];
        }
    }
    if (ch == 0 && tid == 0) rowptr[r * (N_ + 1) + N_] = E_;
}

__global__ void fill_kernel(const int* __restrict__ src, const int* __restrict__ dst,
                            int* __restrict__ cursor, int* __restrict__ csr_src) {
    int idx = blockIdx.x * 256 + threadIdx.x;
    if (idx < R_ * E_) {
        int r = idx / E_;
        int pos = atomicAdd(&cursor[r * N_ + dst[idx]], 1);
        csr_src[(size_t)r * E_ + pos] = src[idx];
    }
}

// ---------------- MFMA GEMM: Z[r] = A @ Bt[r]^T ----------------
template <int K>
__global__ __launch_bounds__(256) void mfma_gemm_kernel(
        const half_t* __restrict__ A, const half_t* __restrict__ Bt,
        half_t* __restrict__ Z, int M, int Nc) {
    int r = blockIdx.z;
    int wave = threadIdx.x >> 6, lane = threadIdx.x & 63;
    int lrow = lane & 15, lq = lane >> 4;
    int rowA = blockIdx.x * 64 + wave * 16 + lrow;
    int col0 = blockIdx.y * 64;
    const half_t* Btr = Bt + (size_t)r * Nc * K;
    const half_t* aP = A + (size_t)rowA * K + lq * 8;
    bool arow_ok = (rowA < M);
    f16x8 zv8 = {};
    float4v acc[4] = {};
    #pragma unroll
    for (int k0 = 0; k0 < K; k0 += 32) {
        f16x8 af = arow_ok ? *(const f16x8*)(aP + k0) : zv8;
        #pragma unroll
        for (int ct = 0; ct < 4; ++ct) {
            int col = col0 + ct * 16 + lrow;
            f16x8 bf = (col < Nc) ? *(const f16x8*)(Btr + (size_t)col * K + lq * 8 + k0) : zv8;
            acc[ct] = __builtin_amdgcn_mfma_f32_16x16x32_f16(af, bf, acc[ct], 0, 0, 0);
        }
    }
    half_t* Zr = Z + (size_t)r * M * Nc;
    int rbase = blockIdx.x * 64 + wave * 16 + lq * 4;
    #pragma unroll
    for (int ct = 0; ct < 4; ++ct) {
        int col = col0 + ct * 16 + lrow;
        if (col >= Nc) continue;
        #pragma unroll
        for (int g = 0; g < 4; ++g) {
            int row = rbase + g;
            if (row < M) Zr[(size_t)row * Nc + col] = (half_t)acc[ct][g];
        }
    }
}

// ---------------- attention logits ----------------
__global__ __launch_bounds__(256) void attn_kernel(
        const half_t* __restrict__ z, const float* __restrict__ al,
        const float* __restrict__ ar, float* __restrict__ el,
        float* __restrict__ er, int Dd) {
    int wid = blockIdx.x * 4 + (threadIdx.x >> 6);
    int lane = threadIdx.x & 63;
    if (wid >= R_ * N_) return;
    int r = wid / N_;
    const half_t* zr = z + (size_t)wid * (H_ * Dd);
    for (int h = 0; h < H_; ++h) {
        float v = (lane < Dd) ? (float)zr[h * Dd + lane] : 0.f;
        float a = (lane < Dd) ? al[(r * H_ + h) * Dd + lane] : 0.f;
        float b = (lane < Dd) ? ar[(r * H_ + h) * Dd + lane] : 0.f;
        float p = v * a, q = v * b;
        for (int off = 32; off; off >>= 1) {
            p += __shfl_xor(p, off);
            q += __shfl_xor(q, off);
        }
        if (lane == 0) {
            el[(size_t)wid * H_ + h] = p;
            er[(size_t)wid * H_ + h] = q;
        }
    }
}

// ---------------- softmax coefficients ----------------
__global__ __launch_bounds__(256) void coeff_kernel(
        const int* __restrict__ rowptr, const int* __restrict__ csr_src,
        const float* __restrict__ el, const float* __restrict__ er,
        float* __restrict__ ebuf, float* __restrict__ linv) {
    int idx = blockIdx.x * 256 + threadIdx.x;
    if (idx >= R_ * N_) return;
    int r = idx / N_, n = idx - r * N_;
    int start = rowptr[r * (N_ + 1) + n];
    int end   = rowptr[r * (N_ + 1) + n + 1];
    const int* cs = csr_src + (size_t)r * E_;
    const float* elr = el + (size_t)r * N_ * H_;
    float* eb = ebuf + (size_t)r * E_ * 4;
    float ev0 = er[idx * H_ + 0], ev1 = er[idx * H_ + 1], ev2 = er[idx * H_ + 2];
    float m0 = -3.0e38f, m1 = -3.0e38f, m2 = -3.0e38f;
    for (int i = start; i < end; ++i) {
        int s = cs[i];
        float e0 = elr[s * H_ + 0] + ev0; e0 = (e0 > 0.f) ? e0 : NEG_SLOPE * e0;
        float e1 = elr[s * H_ + 1] + ev1; e1 = (e1 > 0.f) ? e1 : NEG_SLOPE * e1;
        float e2 = elr[s * H_ + 2] + ev2; e2 = (e2 > 0.f) ? e2 : NEG_SLOPE * e2;
        eb[i * 4 + 0] = e0; eb[i * 4 + 1] = e1; eb[i * 4 + 2] = e2;
        m0 = fmaxf(m0, e0); m1 = fmaxf(m1, e1); m2 = fmaxf(m2, e2);
    }
    float l0 = 0.f, l1 = 0.f, l2 = 0.f;
    for (int i = start; i < end; ++i) {
        float c0 = __expf(eb[i * 4 + 0] - m0);
        float c1 = __expf(eb[i * 4 + 1] - m1);
        float c2 = __expf(eb[i * 4 + 2] - m2);
        eb[i * 4 + 0] = c0; eb[i * 4 + 1] = c1; eb[i * 4 + 2] = c2;
        l0 += c0; l1 += c1; l2 += c2;
    }
    linv[idx * H_ + 0] = (l0 > 0.f) ? 1.f / l0 : 0.f;
    linv[idx * H_ + 1] = (l1 > 0.f) ? 1.f / l1 : 0.f;
    linv[idx * H_ + 2] = (l2 > 0.f) ? 1.f / l2 : 0.f;
}

// ---------------- gather + aggregate (vectorized row load, 4-edge unroll) --------
// One wave per (r,dst). Lane l < 3*Dd/4 loads f16x4 at zrow+4l — ONE load
// covers the whole 3-head row. head = l/(Dd/4). 4-edge manual unroll keeps
// 4 full-row gathers in flight. Epilogue: *1/l, +bias, relu, head-sum via
// 2 shuffles, atomicAdd from Dd/4 lanes.
template <int Dd, bool RELU>
__global__ __launch_bounds__(256) void agg3_kernel(
        const int* __restrict__ rowptr, const int* __restrict__ csr_src,
        const half_t* __restrict__ z, const float* __restrict__ ebuf,
        const float* __restrict__ linv, const float* __restrict__ bias,
        float* __restrict__ out, float scale) {
    constexpr int QL = Dd / 4;       // lanes per head (16 or 10)
    constexpr int LACT = 3 * QL;     // active lanes (48 or 30)
    int wid = blockIdx.x * 4 + (threadIdx.x >> 6);
    int lane = threadIdx.x & 63;
    if (wid >= R_ * N_) return;
    int r = wid / N_, n = wid - r * N_;
    int start = rowptr[r * (N_ + 1) + n];
    int end   = rowptr[r * (N_ + 1) + n + 1];
    const int* cs = csr_src + (size_t)r * E_;
    const float4* eb = (const float4*)(ebuf + (size_t)r * E_ * 4);
    const half_t* zr = z + (size_t)r * N_ * (3 * Dd);
    bool act = lane < LACT;
    int hl = act ? lane / QL : 0;
    int dl = act ? lane - hl * QL : 0;
    float a0 = 0.f, a1 = 0.f, a2 = 0.f, a3 = 0.f;
    int i = start;
    for (; i + 4 <= end; i += 4) {
        int s0 = cs[i + 0], s1 = cs[i + 1], s2 = cs[i + 2], s3 = cs[i + 3];
        float4 cA = eb[i + 0], cB = eb[i + 1], cC = eb[i + 2], cD = eb[i + 3];
        f16x4 z0 = {}, z1 = {}, z2 = {}, z3 = {};
        if (act) {
            z0 = *(const f16x4*)(zr + (size_t)s0 * (3 * Dd) + 4 * lane);
            z1 = *(const f16x4*)(zr + (size_t)s1 * (3 * Dd) + 4 * lane);
            z2 = *(const f16x4*)(zr + (size_t)s2 * (3 * Dd) + 4 * lane);
            z3 = *(const f16x4*)(zr + (size_t)s3 * (3 * Dd) + 4 * lane);
        }
        float cv0 = (hl == 0) ? cA.x : (hl == 1) ? cA.y : cA.z;
        float cv1 = (hl == 0) ? cB.x : (hl == 1) ? cB.y : cB.z;
        float cv2 = (hl == 0) ? cC.x : (hl == 1) ? cC.y : cC.z;
        float cv3 = (hl == 0) ? cD.x : (hl == 1) ? cD.y : cD.z;
        a0 += cv0 * (float)z0[0] + cv1 * (float)z1[0] + cv2 * (float)z2[0] + cv3 * (float)z3[0];
        a1 += cv0 * (float)z0[1] + cv1 * (float)z1[1] + cv2 * (float)z2[1] + cv3 * (float)z3[1];
        a2 += cv0 * (float)z0[2] + cv1 * (float)z1[2] + cv2 * (float)z2[2] + cv3 * (float)z3[2];
        a3 += cv0 * (float)z0[3] + cv1 * (float)z1[3] + cv2 * (float)z2[3] + cv3 * (float)z3[3];
    }
    for (; i < end; ++i) {
        int s0 = cs[i];
        float4 cA = eb[i];
        f16x4 z0 = {};
        if (act) z0 = *(const f16x4*)(zr + (size_t)s0 * (3 * Dd) + 4 * lane);
        float cv0 = (hl == 0) ? cA.x : (hl == 1) ? cA.y : cA.z;
        a0 += cv0 * (float)z0[0];
        a1 += cv0 * (float)z0[1];
        a2 += cv0 * (float)z0[2];
        a3 += cv0 * (float)z0[3];
    }
    // epilogue: normalize, bias, relu
    float li = linv[wid * H_ + hl];
    const float* br = bias + r * (3 * Dd) + hl * Dd + 4 * dl;
    float v0 = a0 * li + br[0];
    float v1 = a1 * li + br[1];
    float v2 = a2 * li + br[2];
    float v3 = a3 * li + br[3];
    if (RELU) {
        v0 = fmaxf(v0, 0.f); v1 = fmaxf(v1, 0.f);
        v2 = fmaxf(v2, 0.f); v3 = fmaxf(v3, 0.f);
    }
    // head sum: lane l (<QL) += lanes l+QL, l+2QL
    int i1 = (lane + QL) & 63, i2 = (lane + 2 * QL) & 63;
    v0 += __shfl(v0, i1) + __shfl(v0, i2);
    v1 += __shfl(v1, i1) + __shfl(v1, i2);
    v2 += __shfl(v2, i1) + __shfl(v2, i2);
    v3 += __shfl(v3, i1) + __shfl(v3, i2);
    if (lane < QL) {
        float* op = out + (size_t)n * Dd + 4 * lane;
        atomicAdd(op + 0, v0 * scale);
        atomicAdd(op + 1, v1 * scale);
        atomicAdd(op + 2, v2 * scale);
        atomicAdd(op + 3, v3 * scale);
    }
}

// ---------------- launch ----------------
static inline size_t align256(size_t x) { return (x + 255) & ~(size_t)255; }

extern "C" void kernel_launch(void* const* d_in, const int* in_sizes, int n_in,
                              void* d_out, int out_size, void* d_ws, size_t ws_size,
                              hipStream_t stream) {
    const float* feat = (const float*)d_in[0];
    const int*   src  = (const int*)d_in[1];
    const int*   dst  = (const int*)d_in[2];
    const float* W1   = (const float*)d_in[3];
    const float* al1  = (const float*)d_in[4];
    const float* ar1  = (const float*)d_in[5];
    const float* b1   = (const float*)d_in[6];
    const float* W2   = (const float*)d_in[7];
    const float* al2  = (const float*)d_in[8];
    const float* ar2  = (const float*)d_in[9];
    const float* b2   = (const float*)d_in[10];
    float* out = (float*)d_out;

    // workspace carve
    char* ws = (char*)d_ws;
    size_t off = 0;
    half_t* zbuf = (half_t*)(ws + off); off += align256((size_t)R_ * N_ * (H_ * HID_) * 2);
    half_t* featH = (half_t*)(ws + off); off += align256((size_t)N_ * IN_ * 2);
    half_t* h1h  = (half_t*)(ws + off); off += align256((size_t)N_ * HID_ * 2);
    half_t* W1t  = (half_t*)(ws + off); off += align256((size_t)R_ * (H_ * HID_) * IN_ * 2);
    half_t* W2t  = (half_t*)(ws + off); off += align256((size_t)R_ * (H_ * C_) * HID_ * 2);
    float* el   = (float*)(ws + off); off += align256((size_t)R_ * N_ * H_ * 4);
    float* er   = (float*)(ws + off); off += align256((size_t)R_ * N_ * H_ * 4);
    float* h1f  = (float*)(ws + off); off += align256((size_t)N_ * HID_ * 4);
    int* deg    = (int*)(ws + off);   off += align256((size_t)R_ * N_ * 4);
    int* rowptr = (int*)(ws + off);   off += align256((size_t)R_ * (N_ + 1) * 4);
    int* cursor = (int*)(ws + off);   off += align256((size_t)R_ * N_ * 4);
    int* bsum   = (int*)(ws + off);   off += align256((size_t)R_ * NCH2 * 4);
    int* csr    = (int*)(ws + off);   off += align256((size_t)R_ * E_ * 4);
    float* ebuf = (float*)(ws + off); off += align256((size_t)R_ * E_ * 4 * 4);
    float* linv = (float*)(ws + off); off += align256((size_t)R_ * N_ * H_ * 4);
    (void)ws_size; (void)n_in; (void)in_sizes; (void)out_size;

    const int EDGE_BLOCKS = (R_ * E_ + 255) / 256;     // 4688
    const int ROW_TILES = (N_ + 63) / 64;              // 782
    const int NODE_BLOCKS = (R_ * N_ + 255) / 256;     // 586
    const int WAVE_BLOCKS = (R_ * N_) / 4;             // 37500

    // ---- input casts / weight transposes ----
    cast_f2h_kernel<<<(N_ * IN_ / 4 + 255) / 256, 256, 0, stream>>>(feat, featH, N_ * IN_ / 4);
    transcast_kernel<<<(R_ * IN_ * (H_ * HID_) + 255) / 256, 256, 0, stream>>>(W1, W1t, IN_, H_ * HID_);
    transcast_kernel<<<(R_ * HID_ * (H_ * C_) + 255) / 256, 256, 0, stream>>>(W2, W2t, HID_, H_ * C_);

    // ---- CSR build (shared by both layers) ----
    zero_kernel<<<NODE_BLOCKS, 256, 0, stream>>>((float*)deg, (size_t)R_ * N_);
    hist_kernel<<<EDGE_BLOCKS, 256, 0, stream>>>(dst, deg);
    scanA_kernel<<<dim3(NCH, R_), 256, 0, stream>>>(deg, bsum);
    scanB_kernel<<<1, 64, 0, stream>>>(bsum);
    scanC_kernel<<<dim3(NCH, R_), 256, 0, stream>>>(deg, bsum, rowptr, cursor);
    fill_kernel<<<EDGE_BLOCKS, 256, 0, stream>>>(src, dst, cursor, csr);

    // ---- layer 1: IN -> H*HID, relu ----
    mfma_gemm_kernel<IN_><<<dim3(ROW_TILES, 3, R_), 256, 0, stream>>>(
        featH, W1t, zbuf, N_, H_ * HID_);
    attn_kernel<<<WAVE_BLOCKS, 256, 0, stream>>>(zbuf, al1, ar1, el, er, HID_);
    coeff_kernel<<<NODE_BLOCKS, 256, 0, stream>>>(rowptr, csr, el, er, ebuf, linv);
    zero_kernel<<<((size_t)N_ * HID_ + 255) / 256, 256, 0, stream>>>(h1f, (size_t)N_ * HID_);
    agg3_kernel<HID_, true><<<WAVE_BLOCKS, 256, 0, stream>>>(
        rowptr, csr, zbuf, ebuf, linv, b1, h1f, 1.f / (H_ * R_));
    cast_f2h_kernel<<<(N_ * HID_ / 4 + 255) / 256, 256, 0, stream>>>(h1f, h1h, N_ * HID_ / 4);

    // ---- layer 2: HID -> H*C, no relu ----
    mfma_gemm_kernel<HID_><<<dim3(ROW_TILES, 2, R_), 256, 0, stream>>>(
        h1h, W2t, zbuf, N_, H_ * C_);
    attn_kernel<<<WAVE_BLOCKS, 256, 0, stream>>>(zbuf, al2, ar2, el, er, C_);
    coeff_kernel<<<NODE_BLOCKS, 256, 0, stream>>>(rowptr, csr, el, er, ebuf, linv);
    zero_kernel<<<((size_t)N_ * C_ + 255) / 256, 256, 0, stream>>>(out, (size_t)N_ * C_);
    agg3_kernel<C_, false><<<WAVE_BLOCKS, 256, 0, stream>>>(
        rowptr, csr, zbuf, ebuf, linv, b2, out, 1.f / (H_ * R_));
}